// Round 1
// baseline (6126.520 us; speedup 1.0000x reference)
//
#include <hip/hip_runtime.h>
#include <hip/hip_cooperative_groups.h>

typedef __attribute__((ext_vector_type(8))) short short8;   // 8 bf16 (4 VGPRs)
typedef __attribute__((ext_vector_type(4))) float f32x4;
typedef __attribute__((ext_vector_type(4))) float floatx4;
typedef __attribute__((ext_vector_type(4))) unsigned int uintx4;
typedef __attribute__((ext_vector_type(2))) unsigned int uintx2;

#define MFMA16(a, b, c) __builtin_amdgcn_mfma_f32_16x16x32_bf16(a, b, c, 0, 0, 0)

// B=64, S=512, V=32000, D=1024, H=1024, C=1000
#define SB_ROWS 32768   // S*B, row m = s*64 + b

#define AT_LOAD_U64(p)  __hip_atomic_load((p), __ATOMIC_RELAXED, __HIP_MEMORY_SCOPE_AGENT)
#define AT_LOAD_U32(p)  __hip_atomic_load((p), __ATOMIC_RELAXED, __HIP_MEMORY_SCOPE_AGENT)
#define AT_STORE_U32(p, v) __hip_atomic_store((p), (v), __ATOMIC_RELAXED, __HIP_MEMORY_SCOPE_AGENT)

__device__ __forceinline__ unsigned short f2bf(float f) {
  unsigned u = __float_as_uint(f);
  u += 0x7fffu + ((u >> 16) & 1u);          // RNE
  return (unsigned short)(u >> 16);
}
__device__ __forceinline__ float bf2f(short s) {
  return __uint_as_float(((unsigned)(unsigned short)s) << 16);
}
__device__ __forceinline__ float sigmoidf_(float x) {
  return 1.0f / (1.0f + __expf(-x));
}
__device__ __forceinline__ void gld_lds16(const void* g, void* l) {
  __builtin_amdgcn_global_load_lds(
      (const __attribute__((address_space(1))) unsigned int*)g,
      (__attribute__((address_space(3))) unsigned int*)l, 16, 0, 0);
}

// ---------------- f32 -> bf16 cast (n multiple of 4) ----------------
__global__ __launch_bounds__(256) void cast_bf16_k(const float* __restrict__ src,
                                                   short* __restrict__ dst, int n) {
  int i = (blockIdx.x * 256 + threadIdx.x) * 4;
  if (i >= n) return;
  floatx4 v = *(const floatx4*)(src + i);
  unsigned int lo = f2bf(v.x) | ((unsigned)f2bf(v.y) << 16);
  unsigned int hi = f2bf(v.z) | ((unsigned)f2bf(v.w) << 16);
  uintx2 o; o.x = lo; o.y = hi;
  *(uintx2*)(dst + i) = o;
}

// ---------------- embedding gather: xe16[s*64+b][d] = bf16(emb[x[b][s]][d]) ----------------
__global__ __launch_bounds__(128) void embed_gather(const int* __restrict__ x,
                                                    const float* __restrict__ emb,
                                                    short* __restrict__ xe16) {
  const int m = blockIdx.x;            // s*64 + b
  const int s = m >> 6, b = m & 63;
  const int idx = x[b * 512 + s];
  const int d0 = threadIdx.x * 8;
  const float* src = emb + (size_t)idx * 1024 + d0;
  floatx4 a = *(const floatx4*)src;
  floatx4 c = *(const floatx4*)(src + 4);
  uintx4 o;
  o.x = f2bf(a.x) | ((unsigned)f2bf(a.y) << 16);
  o.y = f2bf(a.z) | ((unsigned)f2bf(a.w) << 16);
  o.z = f2bf(c.x) | ((unsigned)f2bf(c.y) << 16);
  o.w = f2bf(c.z) | ((unsigned)f2bf(c.w) << 16);
  *(uintx4*)(xe16 + (size_t)m * 1024 + d0) = o;
}

// ---------------- batched projections: xfi[m][0:1024]=xe@Wf^T+bf, [1024:2048]=xe@Wi^T+bi ----
__global__ __launch_bounds__(256, 2) void gemm_xfi(const short* __restrict__ A,
                                                   const short* __restrict__ Wf,
                                                   const short* __restrict__ Wi,
                                                   const float* __restrict__ bfp,
                                                   const float* __restrict__ bip,
                                                   float* __restrict__ Cout) {
  __shared__ __align__(16) short As[128 * 64];
  __shared__ __align__(16) short Bs[128 * 64];
  const int tid = threadIdx.x;
  const int wave = tid >> 6, lane = tid & 63;
  const int quad = lane >> 4, l15 = lane & 15;
  const int nt = blockIdx.x & 15;
  const long m0 = (long)(blockIdx.x >> 4) * 128;
  const int n0 = nt * 128;
  const short* Bm = (n0 < 1024) ? Wf : Wi;
  const int nb = (n0 < 1024) ? n0 : n0 - 1024;
  const int wm = (wave >> 1) * 64, wn = (wave & 1) * 64;

  f32x4 acc[4][4] = {};
  const int cb = wave * 4;

  for (int k0 = 0; k0 < 1024; k0 += 64) {
    __syncthreads();
#pragma unroll
    for (int q = 0; q < 4; ++q) {
      int Cc = (cb + q) * 64 + lane;
      int row = Cc >> 3, slot = Cc & 7;
      int gk = k0 + ((slot ^ (row & 7)) << 3);
      gld_lds16(A + (m0 + row) * 1024 + gk, As + (size_t)(cb + q) * 512);
      gld_lds16(Bm + (long)(nb + row) * 1024 + gk, Bs + (size_t)(cb + q) * 512);
    }
    __syncthreads();
#pragma unroll
    for (int ks = 0; ks < 2; ++ks) {
      short8 av[4], bv[4];
      const int slin = ks * 4 + quad;
#pragma unroll
      for (int i = 0; i < 4; ++i) {
        int row = wm + i * 16 + l15;
        int slot = slin ^ (row & 7);
        av[i] = *(const short8*)&As[row * 64 + slot * 8];
      }
#pragma unroll
      for (int j = 0; j < 4; ++j) {
        int col = wn + j * 16 + l15;
        int slot = slin ^ (col & 7);
        bv[j] = *(const short8*)&Bs[col * 64 + slot * 8];
      }
#pragma unroll
      for (int i = 0; i < 4; ++i)
#pragma unroll
        for (int j = 0; j < 4; ++j) acc[i][j] = MFMA16(av[i], bv[j], acc[i][j]);
    }
  }
#pragma unroll
  for (int j = 0; j < 4; ++j) {
    int ng = n0 + wn + j * 16 + l15;
    float bias = (ng < 1024) ? bfp[ng] : bip[ng - 1024];
#pragma unroll
    for (int i = 0; i < 4; ++i)
#pragma unroll
      for (int r = 0; r < 4; ++r) {
        long m = m0 + wm + i * 16 + quad * 4 + r;
        Cout[m * 2048 + ng] = acc[i][j][r] + bias;
      }
  }
}

// ---------------- cooperative recurrence: 512 steps, 64 blocks x 512 thr ----------------
// R6: flag-based producer/consumer sync (no central barrier), k-split across 8 waves.
//  - waves 0-3 (kh=0): k=0..511 + gating/stores/flag-publish for rows w3*16..+15
//  - waves 4-7 (kh=1): k=512..1023, partials via LDS (double-buffered, 1 barrier/step)
//  - flags[block*4+rowgroup] = steps completed by that producing wave (monotonic).
//    Consumers poll ONLY their 32 actual producers (same rowgroup, their k-half's blocks).
//  - Safety: writing h(t+2) transitively requires every block consumed h(t) (flag order),
//    so the 2-buffer ping-pong is race-free without a grid barrier.
//  - xfi/xe prefetch issued AFTER flag publish -> HBM latency hides under poll+MFMA.
__global__ __launch_bounds__(512, 1) void ran_scan(const float* __restrict__ xfi,
                                                   const short* __restrict__ xe16,
                                                   const short* __restrict__ Uf,
                                                   const short* __restrict__ Ui,
                                                   short* __restrict__ h16,
                                                   unsigned* __restrict__ flg) {
  __shared__ __align__(16) short Us[2][16 * 1024];   // 64 KB
  __shared__ float Pr[2][4][512];                    // 16 KB partials (parity, rowgrp, k*64+lane)
  const int tid = threadIdx.x;
  const int wave = tid >> 6, lane = tid & 63;
  const int w3 = wave & 3, kh = wave >> 2;           // row-group, k-half
  const int quad = lane >> 4, l15 = lane & 15;
  const int c0 = blockIdx.x * 16;
  const int rw = w3 * 16;
  const int colg = c0 + l15;

  // stage U rows c0..c0+15 for both gates; 16B-chunk XOR swizzle (as before, 512 thr)
#pragma unroll
  for (int g = 0; g < 2; ++g) {
    const short* U = g ? Ui : Uf;
    for (int it = 0; it < 4; ++it) {
      int Cc = it * 512 + tid;         // 0..2047
      int row = Cc >> 7;               // 0..15
      int slt = Cc & 127;
      int gsl = (slt & ~7) | ((slt ^ row) & 7);
      short8 v = *(const short8*)&U[(size_t)(c0 + row) * 1024 + gsl * 8];
      *(short8*)&Us[g][row * 1024 + slt * 8] = v;
    }
  }

  float hreg[4] = {0.f, 0.f, 0.f, 0.f};   // fp32 h master (waves 0-3 only)
  float nxf[4], nxi[4], nxe[4];           // current-step inputs (prefetched)
  if (kh == 0) {
#pragma unroll
    for (int r = 0; r < 4; ++r) {
      int rb = rw + quad * 4 + r;
      nxf[r] = xfi[(size_t)rb * 2048 + colg];
      nxi[r] = xfi[(size_t)rb * 2048 + 1024 + colg];
      nxe[r] = bf2f(xe16[(size_t)rb * 1024 + colg]);
    }
  }
  __syncthreads();   // Us staged

  union U8 { unsigned long long q[2]; short8 s; };

  for (int t = 0; t < 512; ++t) {
    const int rp = t & 1;
    f32x4 af0 = {0.f, 0.f, 0.f, 0.f}, af1 = af0, ai0 = af0, ai1 = af0;
    if (t > 0) {
      // wait for my 32 producers: blocks [kh*32, kh*32+32), row-group w3
      {
        const unsigned* fp = flg + ((kh * 32 + (lane & 31)) * 4 + w3);
        while (AT_LOAD_U32(fp) < (unsigned)t) {}
        asm volatile("" ::: "memory");
      }
      // A = h rows rw..rw+15, k-half kh: 32 coherent u64 loads issued as one batch
      const unsigned long long* hq =
          (const unsigned long long*)(h16 + (size_t)rp * 65536);
      const size_t base = (size_t)(rw + l15) * 256 + kh * 128 + quad * 2;  // u64 units
      unsigned long long Aq[32];
#pragma unroll
      for (int c = 0; c < 16; ++c) {
        Aq[2 * c]     = AT_LOAD_U64(hq + base + c * 8);
        Aq[2 * c + 1] = AT_LOAD_U64(hq + base + c * 8 + 1);
      }
#pragma unroll
      for (int c = 0; c < 16; ++c) {
        const int kc = kh * 16 + c;
        const int slin = kc * 4 + quad;
        const int slt = (slin & ~7) | ((slin ^ l15) & 7);
        U8 u; u.q[0] = Aq[2 * c]; u.q[1] = Aq[2 * c + 1];
        short8 a = u.s;
        short8 bfv = *(const short8*)&Us[0][l15 * 1024 + slt * 8];
        short8 biv = *(const short8*)&Us[1][l15 * 1024 + slt * 8];
        if (c & 1) { af1 = MFMA16(a, bfv, af1); ai1 = MFMA16(a, biv, ai1); }
        else       { af0 = MFMA16(a, bfv, af0); ai0 = MFMA16(a, biv, ai0); }
      }
    }
    // k-half 1 publishes partials to LDS; single barrier; k-half 0 reduces + gates
    if (kh == 1) {
#pragma unroll
      for (int r = 0; r < 4; ++r) {
        Pr[rp][w3][r * 64 + lane]       = af0[r] + af1[r];
        Pr[rp][w3][(4 + r) * 64 + lane] = ai0[r] + ai1[r];
      }
    }
    __syncthreads();
    if (kh == 0) {
      unsigned short hb[4];
#pragma unroll
      for (int r = 0; r < 4; ++r) {
        float sf = af0[r] + af1[r] + Pr[rp][w3][r * 64 + lane];
        float si = ai0[r] + ai1[r] + Pr[rp][w3][(4 + r) * 64 + lane];
        float fg = sigmoidf_(nxf[r] + sf);
        float ig = sigmoidf_(nxi[r] + si);
        float hn = fg * hreg[r] + ig * nxe[r];
        hreg[r] = hn;
        hb[r] = f2bf(hn);
      }
      // publish h as coherent 32-bit stores: lane-xor pairs adjacent columns (verbatim)
      {
        unsigned* hwp = (unsigned*)(h16 + (size_t)(rp ^ 1) * 65536);
        unsigned p01 = hb[0] | ((unsigned)hb[1] << 16);
        unsigned p23 = hb[2] | ((unsigned)hb[3] << 16);
        unsigned q01 = (unsigned)__shfl_xor((int)p01, 1, 64);
        unsigned q23 = (unsigned)__shfl_xor((int)p23, 1, 64);
        const int cph = (c0 + (l15 & ~1)) >> 1;   // dword col index
        const int rbase = rw + quad * 4;
        if (!(l15 & 1)) {
          unsigned dw0 = (p01 & 0xffffu) | (q01 << 16);
          unsigned dw1 = (p01 >> 16) | (q01 & 0xffff0000u);
          AT_STORE_U32(hwp + (size_t)(rbase + 0) * 512 + cph, dw0);
          AT_STORE_U32(hwp + (size_t)(rbase + 1) * 512 + cph, dw1);
        } else {
          unsigned dw2 = (q23 & 0xffffu) | (p23 << 16);
          unsigned dw3 = (q23 >> 16) | (p23 & 0xffff0000u);
          AT_STORE_U32(hwp + (size_t)(rbase + 2) * 512 + cph, dw2);
          AT_STORE_U32(hwp + (size_t)(rbase + 3) * 512 + cph, dw3);
        }
      }
      if (t < 511) {
        // stores ack'd at LLC, then this wave's flag, then prefetch (off critical path)
        asm volatile("s_waitcnt vmcnt(0)" ::: "memory");
        if (lane == 0) AT_STORE_U32(flg + (blockIdx.x * 4 + w3), (unsigned)(t + 1));
        const size_t mb = (size_t)(t + 1) * 64;
#pragma unroll
        for (int r = 0; r < 4; ++r) {
          size_t mrow = mb + (rw + quad * 4 + r);
          nxf[r] = xfi[mrow * 2048 + colg];
          nxi[r] = xfi[mrow * 2048 + 1024 + colg];
          nxe[r] = bf2f(xe16[mrow * 1024 + colg]);
        }
      }
    }
  }
  // t=511 wrote buffer 0 (write-through, at LLC). fc_kernel launch's implicit
  // acquire (kernel boundary) makes it visible — same mechanism as before.
}

// ---------------- final FC: out[b][c] = h @ fc_w^T + fc_b (c < 1000) ----------------
__global__ __launch_bounds__(256) void fc_kernel(const short* __restrict__ h16,
                                                 const short* __restrict__ fcw16,
                                                 const float* __restrict__ fcb,
                                                 float* __restrict__ out) {
  const int tid = threadIdx.x;
  const int wave = tid >> 6, lane = tid & 63;
  const int quad = lane >> 4, l15 = lane & 15;
  const int c = blockIdx.x * 64 + wave * 16 + l15;
  f32x4 acc[4] = {};
#pragma unroll
  for (int kc = 0; kc < 32; ++kc) {
    int k = kc * 32 + quad * 8;
    short8 b = *(const short8*)&fcw16[(size_t)c * 1024 + k];
#pragma unroll
    for (int i = 0; i < 4; ++i) {
      short8 a = *(const short8*)&h16[(size_t)(i * 16 + l15) * 1024 + k];
      acc[i] = MFMA16(a, b, acc[i]);
    }
  }
  if (c < 1000) {
    float bias = fcb[c];
#pragma unroll
    for (int i = 0; i < 4; ++i)
#pragma unroll
      for (int r = 0; r < 4; ++r) {
        int m = i * 16 + quad * 4 + r;
        out[m * 1000 + c] = acc[i][r] + bias;
      }
  }
}

extern "C" void kernel_launch(void* const* d_in, const int* in_sizes, int n_in,
                              void* d_out, int out_size, void* d_ws, size_t ws_size,
                              hipStream_t stream) {
  const int* x = (const int*)d_in[0];
  const float* emb = (const float*)d_in[1];
  const float* Wf_w = (const float*)d_in[2];
  const float* Wf_b = (const float*)d_in[3];
  const float* Uf_w = (const float*)d_in[4];
  const float* Wi_w = (const float*)d_in[5];
  const float* Wi_b = (const float*)d_in[6];
  const float* Ui_w = (const float*)d_in[7];
  const float* fc_w = (const float*)d_in[8];
  const float* fc_b = (const float*)d_in[9];
  float* out = (float*)d_out;

  char* ws = (char*)d_ws;
  size_t off = 0;
  auto alloc = [&](size_t bytes) {
    char* p = ws + off;
    off += (bytes + 255) & ~(size_t)255;
    return p;
  };
  short* xe16 = (short*)alloc((size_t)SB_ROWS * 1024 * 2);       // 64 MB
  float* xfi  = (float*)alloc((size_t)SB_ROWS * 2048 * 4);       // 256 MB
  short* Wf16 = (short*)alloc(1024ull * 1024 * 2);
  short* Wi16 = (short*)alloc(1024ull * 1024 * 2);
  short* Uf16 = (short*)alloc(1024ull * 1024 * 2);
  short* Ui16 = (short*)alloc(1024ull * 1024 * 2);
  short* fcw16 = (short*)alloc(1024ull * 1024 * 2);
  short* h16 = (short*)alloc(2ull * 65536 * 2);                  // ping-pong bf16 h
  unsigned* flg = (unsigned*)alloc(256 * sizeof(unsigned));      // per-(block,rowgroup) flags
  if (off > ws_size) return;

  hipMemsetAsync((void*)flg, 0, 256 * sizeof(unsigned), stream);
  cast_bf16_k<<<1024, 256, 0, stream>>>(Wf_w, Wf16, 1024 * 1024);
  cast_bf16_k<<<1024, 256, 0, stream>>>(Wi_w, Wi16, 1024 * 1024);
  cast_bf16_k<<<1024, 256, 0, stream>>>(Uf_w, Uf16, 1024 * 1024);
  cast_bf16_k<<<1024, 256, 0, stream>>>(Ui_w, Ui16, 1024 * 1024);
  cast_bf16_k<<<1000, 256, 0, stream>>>(fc_w, fcw16, 1000 * 1024);
  embed_gather<<<SB_ROWS, 128, 0, stream>>>(x, emb, xe16);
  gemm_xfi<<<(SB_ROWS / 128) * 16, 256, 0, stream>>>(xe16, Wf16, Wi16, Wf_b, Wi_b, xfi);

  const float* xfi_a = xfi;
  const short* xe_a = xe16;
  const short* uf_a = Uf16;
  const short* ui_a = Ui16;
  short* h16_a = h16;
  unsigned* flg_a = flg;
  void* args[] = {(void*)&xfi_a, (void*)&xe_a, (void*)&uf_a,
                  (void*)&ui_a,  (void*)&h16_a, (void*)&flg_a};
  (void)hipLaunchCooperativeKernel((void*)ran_scan, dim3(64), dim3(512), args, 0, stream);

  // after t=511 (odd): final h is in buffer 0
  fc_kernel<<<16, 256, 0, stream>>>(h16, fcw16, fc_b, out);
}

// Round 3
// 4063.608 us; speedup vs baseline: 1.5077x; 1.5077x over previous
//
#include <hip/hip_runtime.h>
#include <hip/hip_cooperative_groups.h>

typedef __attribute__((ext_vector_type(8))) short short8;   // 8 bf16 (4 VGPRs)
typedef __attribute__((ext_vector_type(4))) float f32x4;
typedef __attribute__((ext_vector_type(4))) float floatx4;
typedef __attribute__((ext_vector_type(4))) unsigned int uintx4;
typedef __attribute__((ext_vector_type(2))) unsigned int uintx2;
typedef __attribute__((ext_vector_type(4))) unsigned int u32x4;

#define MFMA16(a, b, c) __builtin_amdgcn_mfma_f32_16x16x32_bf16(a, b, c, 0, 0, 0)

// B=64, S=512, V=32000, D=1024, H=1024, C=1000
#define SB_ROWS 32768   // S*B, row m = s*64 + b

#define AT_LOAD_U32(p)  __hip_atomic_load((p), __ATOMIC_RELAXED, __HIP_MEMORY_SCOPE_AGENT)
#define AT_STORE_U32(p, v) __hip_atomic_store((p), (v), __ATOMIC_RELAXED, __HIP_MEMORY_SCOPE_AGENT)

__device__ __forceinline__ unsigned short f2bf(float f) {
  unsigned u = __float_as_uint(f);
  u += 0x7fffu + ((u >> 16) & 1u);          // RNE
  return (unsigned short)(u >> 16);
}
__device__ __forceinline__ float bf2f(short s) {
  return __uint_as_float(((unsigned)(unsigned short)s) << 16);
}
__device__ __forceinline__ float sigmoidf_(float x) {
  return 1.0f / (1.0f + __expf(-x));
}
__device__ __forceinline__ void gld_lds16(const void* g, void* l) {
  __builtin_amdgcn_global_load_lds(
      (const __attribute__((address_space(1))) unsigned int*)g,
      (__attribute__((address_space(3))) unsigned int*)l, 16, 0, 0);
}

// ---------------- f32 -> bf16 cast (n multiple of 4) ----------------
__global__ __launch_bounds__(256) void cast_bf16_k(const float* __restrict__ src,
                                                   short* __restrict__ dst, int n) {
  int i = (blockIdx.x * 256 + threadIdx.x) * 4;
  if (i >= n) return;
  floatx4 v = *(const floatx4*)(src + i);
  unsigned int lo = f2bf(v.x) | ((unsigned)f2bf(v.y) << 16);
  unsigned int hi = f2bf(v.z) | ((unsigned)f2bf(v.w) << 16);
  uintx2 o; o.x = lo; o.y = hi;
  *(uintx2*)(dst + i) = o;
}

// ---------------- embedding gather: xe16[s*64+b][d] = bf16(emb[x[b][s]][d]) ----------------
__global__ __launch_bounds__(128) void embed_gather(const int* __restrict__ x,
                                                    const float* __restrict__ emb,
                                                    short* __restrict__ xe16) {
  const int m = blockIdx.x;            // s*64 + b
  const int s = m >> 6, b = m & 63;
  const int idx = x[b * 512 + s];
  const int d0 = threadIdx.x * 8;
  const float* src = emb + (size_t)idx * 1024 + d0;
  floatx4 a = *(const floatx4*)src;
  floatx4 c = *(const floatx4*)(src + 4);
  uintx4 o;
  o.x = f2bf(a.x) | ((unsigned)f2bf(a.y) << 16);
  o.y = f2bf(a.z) | ((unsigned)f2bf(a.w) << 16);
  o.z = f2bf(c.x) | ((unsigned)f2bf(c.y) << 16);
  o.w = f2bf(c.z) | ((unsigned)f2bf(c.w) << 16);
  *(uintx4*)(xe16 + (size_t)m * 1024 + d0) = o;
}

// ---------------- batched projections: xfi[m][0:1024]=xe@Wf^T+bf, [1024:2048]=xe@Wi^T+bi ----
__global__ __launch_bounds__(256, 2) void gemm_xfi(const short* __restrict__ A,
                                                   const short* __restrict__ Wf,
                                                   const short* __restrict__ Wi,
                                                   const float* __restrict__ bfp,
                                                   const float* __restrict__ bip,
                                                   float* __restrict__ Cout) {
  __shared__ __align__(16) short As[128 * 64];
  __shared__ __align__(16) short Bs[128 * 64];
  const int tid = threadIdx.x;
  const int wave = tid >> 6, lane = tid & 63;
  const int quad = lane >> 4, l15 = lane & 15;
  const int nt = blockIdx.x & 15;
  const long m0 = (long)(blockIdx.x >> 4) * 128;
  const int n0 = nt * 128;
  const short* Bm = (n0 < 1024) ? Wf : Wi;
  const int nb = (n0 < 1024) ? n0 : n0 - 1024;
  const int wm = (wave >> 1) * 64, wn = (wave & 1) * 64;

  f32x4 acc[4][4] = {};
  const int cb = wave * 4;

  for (int k0 = 0; k0 < 1024; k0 += 64) {
    __syncthreads();
#pragma unroll
    for (int q = 0; q < 4; ++q) {
      int Cc = (cb + q) * 64 + lane;
      int row = Cc >> 3, slot = Cc & 7;
      int gk = k0 + ((slot ^ (row & 7)) << 3);
      gld_lds16(A + (m0 + row) * 1024 + gk, As + (size_t)(cb + q) * 512);
      gld_lds16(Bm + (long)(nb + row) * 1024 + gk, Bs + (size_t)(cb + q) * 512);
    }
    __syncthreads();
#pragma unroll
    for (int ks = 0; ks < 2; ++ks) {
      short8 av[4], bv[4];
      const int slin = ks * 4 + quad;
#pragma unroll
      for (int i = 0; i < 4; ++i) {
        int row = wm + i * 16 + l15;
        int slot = slin ^ (row & 7);
        av[i] = *(const short8*)&As[row * 64 + slot * 8];
      }
#pragma unroll
      for (int j = 0; j < 4; ++j) {
        int col = wn + j * 16 + l15;
        int slot = slin ^ (col & 7);
        bv[j] = *(const short8*)&Bs[col * 64 + slot * 8];
      }
#pragma unroll
      for (int i = 0; i < 4; ++i)
#pragma unroll
        for (int j = 0; j < 4; ++j) acc[i][j] = MFMA16(av[i], bv[j], acc[i][j]);
    }
  }
#pragma unroll
  for (int j = 0; j < 4; ++j) {
    int ng = n0 + wn + j * 16 + l15;
    float bias = (ng < 1024) ? bfp[ng] : bip[ng - 1024];
#pragma unroll
    for (int i = 0; i < 4; ++i)
#pragma unroll
      for (int r = 0; r < 4; ++r) {
        long m = m0 + wm + i * 16 + quad * 4 + r;
        Cout[m * 2048 + ng] = acc[i][j][r] + bias;
      }
  }
}

// ---------------- cooperative recurrence: 512 steps, 64 blocks x 512 thr ----------------
// R7b: block-level flags + throttled __all/s_sleep poll + forced single-RT A-load.
//  - waves 0-3 (kh=0): k=0..511, gating, h-stores, prefetch; waves 4-7 (kh=1): k=512..1023,
//    partials through LDS (parity double-buffer), 2 intra-block barriers per step.
//  - flg[block] = steps completed by that block (monotonic, agent store by tid0 after
//    barrier#2; each producer wave did s_waitcnt vmcnt(0) on its h-stores before barrier#2,
//    so flag==t+1 implies the whole 2KB h-tile is at the LLC).
//  - consumers poll only their k-half's 32 producer blocks (32 contiguous dwords, 1-2 lines),
//    __all-reduced, s_sleep(1) backoff.
//  - A-tile read: 16x global_load_dwordx4 (offset:N sc0 sc1 — modifiers AFTER offset on
//    flat/global!) via asm "=&v", 64 VGPRs live -> vmcnt(8)/consume/vmcnt(0)/consume:
//    ONE LLC round-trip instead of 2-4 chained.
//  - Race-freedom across blocks: h-stores of step t+1 happen after barrier#1, which is after
//    BOTH halves' polls (jointly all 64 blocks >= t), i.e. every reader of buffer parity
//    (t&1) is done before it is overwritten. Pr parity is safe via the intra-block barriers.
__global__ __launch_bounds__(512, 1) void ran_scan(const float* __restrict__ xfi,
                                                   const short* __restrict__ xe16,
                                                   const short* __restrict__ Uf,
                                                   const short* __restrict__ Ui,
                                                   short* __restrict__ h16,
                                                   unsigned* __restrict__ flg) {
  __shared__ __align__(16) short Us[2][16 * 1024];   // 64 KB
  __shared__ float Pr[2][4][512];                    // 16 KB partials (parity, rowgrp, ...)
  const int tid = threadIdx.x;
  const int wave = tid >> 6, lane = tid & 63;
  const int w3 = wave & 3, kh = wave >> 2;           // row-group, k-half
  const int quad = lane >> 4, l15 = lane & 15;
  const int c0 = blockIdx.x * 16;
  const int rw = w3 * 16;
  const int colg = c0 + l15;

  // stage U rows c0..c0+15 for both gates; 16B-chunk XOR swizzle
#pragma unroll
  for (int g = 0; g < 2; ++g) {
    const short* U = g ? Ui : Uf;
    for (int it = 0; it < 4; ++it) {
      int Cc = it * 512 + tid;         // 0..2047
      int row = Cc >> 7;               // 0..15
      int slt = Cc & 127;
      int gsl = (slt & ~7) | ((slt ^ row) & 7);
      short8 v = *(const short8*)&U[(size_t)(c0 + row) * 1024 + gsl * 8];
      *(short8*)&Us[g][row * 1024 + slt * 8] = v;
    }
  }

  float hreg[4] = {0.f, 0.f, 0.f, 0.f};   // fp32 h master (waves 0-3 only)
  float nxf[4], nxi[4], nxe[4];           // current-step inputs (prefetched)
  if (kh == 0) {
#pragma unroll
    for (int r = 0; r < 4; ++r) {
      int rb = rw + quad * 4 + r;
      nxf[r] = xfi[(size_t)rb * 2048 + colg];
      nxi[r] = xfi[(size_t)rb * 2048 + 1024 + colg];
      nxe[r] = bf2f(xe16[(size_t)rb * 1024 + colg]);
    }
  }
  __syncthreads();   // Us staged

  const char* hbase = (const char*)h16;
  const size_t aoff =
      ((size_t)(rw + l15) * 256 + (size_t)kh * 128 + (size_t)quad * 2) * 8;  // bytes

#define GLD(dst, off_)                                                       \
  asm volatile("global_load_dwordx4 %0, %1, off offset:" off_ " sc0 sc1"     \
               : "=&v"(dst) : "v"(ab) : "memory")
#define CONSUME(c, Avar)                                                     \
  {                                                                          \
    const int kc = kh * 16 + (c);                                            \
    const int slin = kc * 4 + quad;                                          \
    const int slt = (slin & ~7) | ((slin ^ l15) & 7);                        \
    short8 a = __builtin_bit_cast(short8, Avar);                             \
    short8 bfv = *(const short8*)&Us[0][l15 * 1024 + slt * 8];               \
    short8 biv = *(const short8*)&Us[1][l15 * 1024 + slt * 8];               \
    if ((c) & 1) { af1 = MFMA16(a, bfv, af1); ai1 = MFMA16(a, biv, ai1); }   \
    else         { af0 = MFMA16(a, bfv, af0); ai0 = MFMA16(a, biv, ai0); }   \
  }

  for (int t = 0; t < 512; ++t) {
    const int rp = t & 1;
    f32x4 af0 = {0.f, 0.f, 0.f, 0.f}, af1 = af0, ai0 = af0, ai1 = af0;
    if (t > 0) {
      // ---- throttled poll of my 32 producer blocks ----
      {
        const unsigned* fp = flg + (kh * 32 + (lane & 31));
        unsigned v = AT_LOAD_U32(fp);
        while (!__all((int)(v >= (unsigned)t))) {
          __builtin_amdgcn_s_sleep(1);
          v = AT_LOAD_U32(fp);
        }
        asm volatile("" ::: "memory");
        __builtin_amdgcn_sched_barrier(0);
      }
      // ---- A-tile: 16x dwordx4 coherent loads, one round-trip ----
      const char* ab = hbase + (size_t)rp * 131072 + aoff;
      u32x4 A0, A1, A2, A3, A4, A5, A6, A7, A8, A9, A10, A11, A12, A13, A14, A15;
      GLD(A0, "0");    GLD(A1, "64");   GLD(A2, "128");  GLD(A3, "192");
      GLD(A4, "256");  GLD(A5, "320");  GLD(A6, "384");  GLD(A7, "448");
      GLD(A8, "512");  GLD(A9, "576");  GLD(A10, "640"); GLD(A11, "704");
      GLD(A12, "768"); GLD(A13, "832"); GLD(A14, "896"); GLD(A15, "960");
      asm volatile("s_waitcnt vmcnt(8)" ::: "memory");
      __builtin_amdgcn_sched_barrier(0);
      CONSUME(0, A0) CONSUME(1, A1) CONSUME(2, A2) CONSUME(3, A3)
      CONSUME(4, A4) CONSUME(5, A5) CONSUME(6, A6) CONSUME(7, A7)
      asm volatile("s_waitcnt vmcnt(0)" ::: "memory");
      __builtin_amdgcn_sched_barrier(0);
      CONSUME(8, A8)   CONSUME(9, A9)   CONSUME(10, A10) CONSUME(11, A11)
      CONSUME(12, A12) CONSUME(13, A13) CONSUME(14, A14) CONSUME(15, A15)
    }
    // k-half 1 publishes partials to LDS
    if (kh == 1) {
#pragma unroll
      for (int r = 0; r < 4; ++r) {
        Pr[rp][w3][r * 64 + lane]       = af0[r] + af1[r];
        Pr[rp][w3][(4 + r) * 64 + lane] = ai0[r] + ai1[r];
      }
    }
    __syncthreads();   // barrier #1: partials visible
    if (kh == 0) {
      unsigned short hb[4];
#pragma unroll
      for (int r = 0; r < 4; ++r) {
        float sf = af0[r] + af1[r] + Pr[rp][w3][r * 64 + lane];
        float si = ai0[r] + ai1[r] + Pr[rp][w3][(4 + r) * 64 + lane];
        float fg = sigmoidf_(nxf[r] + sf);
        float ig = sigmoidf_(nxi[r] + si);
        float hn = fg * hreg[r] + ig * nxe[r];
        hreg[r] = hn;
        hb[r] = f2bf(hn);
      }
      // publish h as coherent 32-bit stores: lane-xor pairs adjacent columns
      {
        unsigned* hwp = (unsigned*)(h16 + (size_t)(rp ^ 1) * 65536);
        unsigned p01 = hb[0] | ((unsigned)hb[1] << 16);
        unsigned p23 = hb[2] | ((unsigned)hb[3] << 16);
        unsigned q01 = (unsigned)__shfl_xor((int)p01, 1, 64);
        unsigned q23 = (unsigned)__shfl_xor((int)p23, 1, 64);
        const int cph = (c0 + (l15 & ~1)) >> 1;   // dword col index
        const int rbase = rw + quad * 4;
        if (!(l15 & 1)) {
          unsigned dw0 = (p01 & 0xffffu) | (q01 << 16);
          unsigned dw1 = (p01 >> 16) | (q01 & 0xffff0000u);
          AT_STORE_U32(hwp + (size_t)(rbase + 0) * 512 + cph, dw0);
          AT_STORE_U32(hwp + (size_t)(rbase + 1) * 512 + cph, dw1);
        } else {
          unsigned dw2 = (q23 & 0xffffu) | (p23 << 16);
          unsigned dw3 = (q23 >> 16) | (p23 & 0xffff0000u);
          AT_STORE_U32(hwp + (size_t)(rbase + 2) * 512 + cph, dw2);
          AT_STORE_U32(hwp + (size_t)(rbase + 3) * 512 + cph, dw3);
        }
      }
      asm volatile("s_waitcnt vmcnt(0)" ::: "memory");   // h-stores ack'd at LLC
    }
    __syncthreads();   // barrier #2: all 4 producer waves' stores ack'd
    if (t < 511) {
      if (tid == 0) AT_STORE_U32(flg + blockIdx.x, (unsigned)(t + 1));
      if (kh == 0) {
        // prefetch next step's h-independent inputs (latency hides under next poll)
        const size_t mb = (size_t)(t + 1) * 64;
#pragma unroll
        for (int r = 0; r < 4; ++r) {
          size_t mrow = mb + (rw + quad * 4 + r);
          nxf[r] = xfi[mrow * 2048 + colg];
          nxi[r] = xfi[mrow * 2048 + 1024 + colg];
          nxe[r] = bf2f(xe16[mrow * 1024 + colg]);
        }
      }
    }
  }
#undef GLD
#undef CONSUME
  // t=511 wrote buffer 0 (write-through, at LLC). fc_kernel launch's implicit
  // acquire (kernel boundary) makes it visible.
}

// ---------------- final FC: out[b][c] = h @ fc_w^T + fc_b (c < 1000) ----------------
__global__ __launch_bounds__(256) void fc_kernel(const short* __restrict__ h16,
                                                 const short* __restrict__ fcw16,
                                                 const float* __restrict__ fcb,
                                                 float* __restrict__ out) {
  const int tid = threadIdx.x;
  const int wave = tid >> 6, lane = tid & 63;
  const int quad = lane >> 4, l15 = lane & 15;
  const int c = blockIdx.x * 64 + wave * 16 + l15;
  f32x4 acc[4] = {};
#pragma unroll
  for (int kc = 0; kc < 32; ++kc) {
    int k = kc * 32 + quad * 8;
    short8 b = *(const short8*)&fcw16[(size_t)c * 1024 + k];
#pragma unroll
    for (int i = 0; i < 4; ++i) {
      short8 a = *(const short8*)&h16[(size_t)(i * 16 + l15) * 1024 + k];
      acc[i] = MFMA16(a, b, acc[i]);
    }
  }
  if (c < 1000) {
    float bias = fcb[c];
#pragma unroll
    for (int i = 0; i < 4; ++i)
#pragma unroll
      for (int r = 0; r < 4; ++r) {
        int m = i * 16 + quad * 4 + r;
        out[m * 1000 + c] = acc[i][r] + bias;
      }
  }
}

extern "C" void kernel_launch(void* const* d_in, const int* in_sizes, int n_in,
                              void* d_out, int out_size, void* d_ws, size_t ws_size,
                              hipStream_t stream) {
  const int* x = (const int*)d_in[0];
  const float* emb = (const float*)d_in[1];
  const float* Wf_w = (const float*)d_in[2];
  const float* Wf_b = (const float*)d_in[3];
  const float* Uf_w = (const float*)d_in[4];
  const float* Wi_w = (const float*)d_in[5];
  const float* Wi_b = (const float*)d_in[6];
  const float* Ui_w = (const float*)d_in[7];
  const float* fc_w = (const float*)d_in[8];
  const float* fc_b = (const float*)d_in[9];
  float* out = (float*)d_out;

  char* ws = (char*)d_ws;
  size_t off = 0;
  auto alloc = [&](size_t bytes) {
    char* p = ws + off;
    off += (bytes + 255) & ~(size_t)255;
    return p;
  };
  short* xe16 = (short*)alloc((size_t)SB_ROWS * 1024 * 2);       // 64 MB
  float* xfi  = (float*)alloc((size_t)SB_ROWS * 2048 * 4);       // 256 MB
  short* Wf16 = (short*)alloc(1024ull * 1024 * 2);
  short* Wi16 = (short*)alloc(1024ull * 1024 * 2);
  short* Uf16 = (short*)alloc(1024ull * 1024 * 2);
  short* Ui16 = (short*)alloc(1024ull * 1024 * 2);
  short* fcw16 = (short*)alloc(1024ull * 1024 * 2);
  short* h16 = (short*)alloc(2ull * 65536 * 2);                  // ping-pong bf16 h
  unsigned* flg = (unsigned*)alloc(256 * sizeof(unsigned));      // per-block step flags
  if (off > ws_size) return;

  hipMemsetAsync((void*)flg, 0, 256 * sizeof(unsigned), stream);
  cast_bf16_k<<<1024, 256, 0, stream>>>(Wf_w, Wf16, 1024 * 1024);
  cast_bf16_k<<<1024, 256, 0, stream>>>(Wi_w, Wi16, 1024 * 1024);
  cast_bf16_k<<<1024, 256, 0, stream>>>(Uf_w, Uf16, 1024 * 1024);
  cast_bf16_k<<<1024, 256, 0, stream>>>(Ui_w, Ui16, 1024 * 1024);
  cast_bf16_k<<<1000, 256, 0, stream>>>(fc_w, fcw16, 1000 * 1024);
  embed_gather<<<SB_ROWS, 128, 0, stream>>>(x, emb, xe16);
  gemm_xfi<<<(SB_ROWS / 128) * 16, 256, 0, stream>>>(xe16, Wf16, Wi16, Wf_b, Wi_b, xfi);

  const float* xfi_a = xfi;
  const short* xe_a = xe16;
  const short* uf_a = Uf16;
  const short* ui_a = Ui16;
  short* h16_a = h16;
  unsigned* flg_a = flg;
  void* args[] = {(void*)&xfi_a, (void*)&xe_a, (void*)&uf_a,
                  (void*)&ui_a,  (void*)&h16_a, (void*)&flg_a};
  (void)hipLaunchCooperativeKernel((void*)ran_scan, dim3(64), dim3(512), args, 0, stream);

  // after t=511 (odd): final h is in buffer 0
  fc_kernel<<<16, 256, 0, stream>>>(h16, fcw16, fc_b, out);
}